// Round 6
// baseline (136.810 us; speedup 1.0000x reference)
//
#include <hip/hip_runtime.h>

typedef float v2f __attribute__((ext_vector_type(2)));
typedef float v4f __attribute__((ext_vector_type(4)));

// Problem constants
#define HW      1024   // H*W = BN channel count (spatial positions)
#define NLAYERS 30
#define TPB     512    // 8 waves per channel-block; 8 elems/thread (4 v2f)

// ---------------------------------------------------------------------------
// Packed-f32 VOP3P ops (halve element-pass instruction count vs scalarized).
// ---------------------------------------------------------------------------
static __device__ __forceinline__ v2f pk_fma(v2f a, v2f b, v2f c) {
    v2f d; asm("v_pk_fma_f32 %0, %1, %2, %3" : "=v"(d) : "v"(a), "v"(b), "v"(c));
    return d;
}
static __device__ __forceinline__ v2f pk_add(v2f a, v2f b) {
    v2f d; asm("v_pk_add_f32 %0, %1, %2" : "=v"(d) : "v"(a), "v"(b));
    return d;
}
static __device__ __forceinline__ v2f pk_mul(v2f a, v2f b) {
    v2f d; asm("v_pk_mul_f32 %0, %1, %2" : "=v"(d) : "v"(a), "v"(b));
    return d;
}

// ---------------------------------------------------------------------------
// DPP-based wave64 sum (proven): pure VALU, lane 63 = wave total.
// ---------------------------------------------------------------------------
template <int CTRL, int RMASK>
__device__ __forceinline__ float dpp_add(float x) {
    int t = __builtin_amdgcn_update_dpp(0, __builtin_bit_cast(int, x),
                                        CTRL, RMASK, 0xf, true);
    return x + __builtin_bit_cast(float, t);
}
__device__ __forceinline__ float wave_sum64(float x) {
    x = dpp_add<0x111, 0xf>(x);   // row_shr:1
    x = dpp_add<0x112, 0xf>(x);   // row_shr:2
    x = dpp_add<0x114, 0xf>(x);   // row_shr:4
    x = dpp_add<0x118, 0xf>(x);   // row_shr:8
    x = dpp_add<0x142, 0xa>(x);   // row_bcast15 -> rows 1,3
    x = dpp_add<0x143, 0xc>(x);   // row_bcast31 -> rows 2,3
    return x;                     // lane 63 = wave total
}

// ---------------------------------------------------------------------------
// Fused 30-layer ODE, ONE channel per 512-thread block (8 waves) -> 8192
// waves total = 8 waves/SIMD = 32 waves/CU (HW cap), 4 independent barrier
// domains per CU. Thread t owns elements e = t + 512k (k=0..7), paired as
// 4 v2f; all share matrix index c = t&255. Per layer: one fused pass
// (apply k via med3+Euler, build z_{k+1}, s/q partials), 2 DPP chains,
// lane63 -> LDS, 1 barrier, 8-partial combine, rsqrt. m/dt prefetched.
// ---------------------------------------------------------------------------
__global__ __launch_bounds__(TPB, 8) void ode_hiocc(
    const float* __restrict__ x, const float* __restrict__ delta_t,
    const float* __restrict__ matrices, const float* __restrict__ gamma,
    const float* __restrict__ beta, float* __restrict__ out) {

    const int bid  = blockIdx.x;                      // 0..1023
    const int p    = ((bid & 7) << 7) | (bid >> 3);   // XCD-contiguous channel
    const int t    = threadIdx.x;                     // 0..511
    const int c    = t & 255;                         // matrix element index
    const int wid  = t >> 6;                          // wave 0..7
    const int lane = t & 63;

    __shared__ __align__(16) v2f red[2][8];           // [parity][wave]=(s,q)

    // Gather: e = t + 512k; pair (e, e+2048) into v2f. (e mod 256 == c for all.)
    v2f x1[4], y[4], z[4];
#pragma unroll
    for (int j = 0; j < 4; ++j) {
        const uint32_t e0 = (uint32_t)t + 512u * j;
        x1[j].x = x[(size_t)e0 * HW + p];
        x1[j].y = x[(size_t)(e0 + 2048u) * HW + p];
        y[j] = x1[j];
    }

    const float gp = gamma[p];
    const float bp = beta[p];

    // Layer 0: z0 = x1 + m0*x1 (y0 = x1); reduce; post partials to red[0].
    {
        const float m0 = matrices[c];
        const v2f M0 = {m0, m0};
        v2f s = {0.f, 0.f}, q = {0.f, 0.f};
#pragma unroll
        for (int j = 0; j < 4; ++j) {
            z[j] = pk_fma(M0, x1[j], y[j]);
            s = pk_add(s, z[j]);
            q = pk_fma(z[j], z[j], q);
        }
        const float ss = wave_sum64(s.x + s.y);
        const float qq = wave_sum64(q.x + q.y);
        if (lane == 63) red[0][wid] = (v2f){ss, qq};
    }

    float m_cur  = matrices[256 + c];   // m_1 (builds z_1 in iter k=0)
    float dt_cur = delta_t[0];
    float dt_nxt = delta_t[1];
    __syncthreads();

    for (int k = 0; k < NLAYERS - 1; ++k) {
        // Prefetch m_{k+2}/dt_{k+2}; lands under this layer's body.
        const int k2 = (k + 2 < NLAYERS) ? k + 2 : NLAYERS - 1;
        const float m_nxt = matrices[k2 * 256 + c];
        const float dt_nn = delta_t[k2];

        // Combine 8 wave-partials: 4x ds_read_b128 + 3 v4f adds + 2 adds.
        const int par = k & 1;
        const v4f* r = (const v4f*)&red[par][0];
        const v4f u0 = r[0] + r[1], u1 = r[2] + r[3];
        const v4f u = u0 + u1;
        const float S = u.x + u.z;
        const float Q = u.y + u.w;

        const float dtk  = __builtin_amdgcn_fmed3f(dt_cur, 0.0f, 6.0f);
        const float mean = S * (1.0f / 4096.0f);
        const float var  = fmaf(-mean, mean, Q * (1.0f / 4096.0f));
        const float rstd = rsqrtf(var + 1e-5f);
        const float g    = gp * rstd;            // fold gamma into scale
        const float b    = fmaf(-mean, g, bp);   // fold mean into bias
        const v2f g2 = {g, g}, b2 = {b, b};
        const v2f dt2 = {dtk, dtk};
        const v2f om2 = {1.0f - dtk, 1.0f - dtk};
        const v2f M2  = {m_cur, m_cur};

        // Fused pass: apply layer k, build z_{k+1} and its s/q partials.
        v2f s = {0.f, 0.f}, q = {0.f, 0.f};
#pragma unroll
        for (int j = 0; j < 4; ++j) {
            v2f a = pk_fma(z[j], g2, b2);
            a.x = __builtin_amdgcn_fmed3f(a.x, 0.0f, 6.0f);
            a.y = __builtin_amdgcn_fmed3f(a.y, 0.0f, 6.0f);
            y[j] = pk_mul(om2, y[j]);            // y *= (1-dt)
            y[j] = pk_fma(dt2, a, y[j]);         // y += dt*a
            z[j] = pk_fma(M2, x1[j], y[j]);      // next layer z
            s = pk_add(s, z[j]);
            q = pk_fma(z[j], z[j], q);
        }
        const float ss = wave_sum64(s.x + s.y);
        const float qq = wave_sum64(q.x + q.y);
        if (lane == 63) red[par ^ 1][wid] = (v2f){ss, qq};

        m_cur = m_nxt; dt_cur = dt_nxt; dt_nxt = dt_nn;
        __syncthreads();
    }

    // Final layer (k = 29): combine red[1], apply, scatter out = y + x1.
    {
        const v4f* r = (const v4f*)&red[(NLAYERS - 1) & 1][0];
        const v4f u0 = r[0] + r[1], u1 = r[2] + r[3];
        const v4f u = u0 + u1;
        const float S = u.x + u.z;
        const float Q = u.y + u.w;

        const float dtk  = __builtin_amdgcn_fmed3f(dt_cur, 0.0f, 6.0f);
        const float mean = S * (1.0f / 4096.0f);
        const float var  = fmaf(-mean, mean, Q * (1.0f / 4096.0f));
        const float rstd = rsqrtf(var + 1e-5f);
        const float g    = gp * rstd;
        const float b    = fmaf(-mean, g, bp);
        const v2f g2 = {g, g}, b2 = {b, b};
        const v2f dt2 = {dtk, dtk};
        const v2f om2 = {1.0f - dtk, 1.0f - dtk};

#pragma unroll
        for (int j = 0; j < 4; ++j) {
            v2f a = pk_fma(z[j], g2, b2);
            a.x = __builtin_amdgcn_fmed3f(a.x, 0.0f, 6.0f);
            a.y = __builtin_amdgcn_fmed3f(a.y, 0.0f, 6.0f);
            y[j] = pk_mul(om2, y[j]);
            y[j] = pk_fma(dt2, a, y[j]);
            const v2f o = pk_add(y[j], x1[j]);
            const uint32_t e0 = (uint32_t)t + 512u * j;
            out[(size_t)e0 * HW + p]           = o.x;
            out[(size_t)(e0 + 2048u) * HW + p] = o.y;
        }
    }
}

extern "C" void kernel_launch(void* const* d_in, const int* in_sizes, int n_in,
                              void* d_out, int out_size, void* d_ws, size_t ws_size,
                              hipStream_t stream) {
    const float* x        = (const float*)d_in[0];   // [16,256,32,32]
    const float* delta_t  = (const float*)d_in[1];   // [30,1]
    const float* matrices = (const float*)d_in[2];   // [30,1,1,16,16]
    const float* gamma    = (const float*)d_in[3];   // [1024]
    const float* beta     = (const float*)d_in[4];   // [1024]
    float* out = (float*)d_out;

    ode_hiocc<<<dim3(HW), dim3(TPB), 0, stream>>>(x, delta_t, matrices, gamma, beta, out);
}

// Round 7
// 120.026 us; speedup vs baseline: 1.1398x; 1.1398x over previous
//
#include <hip/hip_runtime.h>

typedef float v2f __attribute__((ext_vector_type(2)));
typedef float v4f __attribute__((ext_vector_type(4)));

#define HW      1024   // H*W = BN channel count (spatial positions)
#define NROWS   4096   // B*C = reduction size per channel
#define NLAYERS 30
#define TPB     256

// ---------------------------------------------------------------------------
// Packed-f32 VOP3P ops.
// ---------------------------------------------------------------------------
static __device__ __forceinline__ v2f pk_fma(v2f a, v2f b, v2f c) {
    v2f d; asm("v_pk_fma_f32 %0, %1, %2, %3" : "=v"(d) : "v"(a), "v"(b), "v"(c));
    return d;
}
static __device__ __forceinline__ v2f pk_add(v2f a, v2f b) {
    v2f d; asm("v_pk_add_f32 %0, %1, %2" : "=v"(d) : "v"(a), "v"(b));
    return d;
}
static __device__ __forceinline__ v2f pk_mul(v2f a, v2f b) {
    v2f d; asm("v_pk_mul_f32 %0, %1, %2" : "=v"(d) : "v"(a), "v"(b));
    return d;
}

// ---------------------------------------------------------------------------
// DPP-based wave64 sum: pure VALU, lane 63 = wave total.
// ---------------------------------------------------------------------------
template <int CTRL, int RMASK>
__device__ __forceinline__ float dpp_add(float x) {
    int t = __builtin_amdgcn_update_dpp(0, __builtin_bit_cast(int, x),
                                        CTRL, RMASK, 0xf, true);
    return x + __builtin_bit_cast(float, t);
}
__device__ __forceinline__ float wave_sum64(float x) {
    x = dpp_add<0x111, 0xf>(x);   // row_shr:1
    x = dpp_add<0x112, 0xf>(x);   // row_shr:2
    x = dpp_add<0x114, 0xf>(x);   // row_shr:4
    x = dpp_add<0x118, 0xf>(x);   // row_shr:8
    x = dpp_add<0x142, 0xa>(x);   // row_bcast15 -> rows 1,3
    x = dpp_add<0x143, 0xc>(x);   // row_bcast31 -> rows 2,3
    return x;                     // lane 63 = wave total
}

// ---------------------------------------------------------------------------
// Generic 64x64-tile transpose: dst[n*M + m] = src[m*N + n]. Coalesced
// loads AND stores; LDS tile padded to 65 -> conflict-free both phases.
// Grid: dim3(N/64, M/64), 256 threads.
// ---------------------------------------------------------------------------
__global__ __launch_bounds__(TPB) void txp64(const float* __restrict__ src,
                                             float* __restrict__ dst,
                                             int M, int N) {
    __shared__ float tile[64][65];
    const int n0 = blockIdx.x * 64;
    const int m0 = blockIdx.y * 64;
    const int tx = threadIdx.x & 63;
    const int ty = threadIdx.x >> 6;    // 0..3
#pragma unroll
    for (int i = 0; i < 16; ++i) {
        const int r = ty + 4 * i;
        tile[r][tx] = src[(size_t)(m0 + r) * N + n0 + tx];
    }
    __syncthreads();
#pragma unroll
    for (int i = 0; i < 16; ++i) {
        const int r = ty + 4 * i;
        dst[(size_t)(n0 + r) * M + m0 + tx] = tile[tx][r];
    }
}

// ---------------------------------------------------------------------------
// Main ODE kernel on TRANSPOSED layout: block p owns row ws[p*4096 .. +4095]
// (contiguous 16 KB). Thread t owns e = 4t + 1024k (+0..3), gathered as
// 4x dwordx4 (fully coalesced, 1 KB/wave-instr). c = (4t+k')&255 -> per-
// thread m quad, one dwordx4 per layer (prefetched). Math/reduction =
// proven R0/R4 structure: fused pass, 2 DPP chains, lane63 -> LDS, one
// barrier, 4-partial combine. Reads complete before layer 0; writes (y+x1)
// land back in the SAME ws row after layer 29 -> no aliasing hazard.
// ---------------------------------------------------------------------------
__global__ __launch_bounds__(TPB, 4) void ode_row(
    float* ws, const float* __restrict__ delta_t,
    const float* __restrict__ matrices, const float* __restrict__ gamma,
    const float* __restrict__ beta) {

    const int p    = blockIdx.x;
    const int t    = threadIdx.x;
    const int wid  = t >> 6;
    const int lane = t & 63;
    const int c0   = (4 * t) & 255;     // matrix quad base for this thread

    __shared__ __align__(16) v2f red[2][4];   // [parity][wave] = (s,q)

    float* row = ws + (size_t)p * NROWS;

    // Coalesced gather: 4x dwordx4.
    v2f x1[8], y[8], z[8];
#pragma unroll
    for (int k = 0; k < 4; ++k) {
        const v4f q4 = *(const v4f*)(row + 4 * t + 1024 * k);
        x1[2 * k]     = (v2f){q4.x, q4.y};
        x1[2 * k + 1] = (v2f){q4.z, q4.w};
        y[2 * k]     = x1[2 * k];
        y[2 * k + 1] = x1[2 * k + 1];
    }

    const float gp = gamma[p];
    const float bp = beta[p];

    // Layer 0: z0 = x1 + m0*x1 (y0 = x1); reduce; post partials to red[0].
    {
        const v4f m4 = *(const v4f*)(matrices + c0);
        const v2f mA = {m4.x, m4.y}, mB = {m4.z, m4.w};
        v2f s = {0.f, 0.f}, q = {0.f, 0.f};
#pragma unroll
        for (int k = 0; k < 4; ++k) {
            z[2 * k] = pk_fma(mA, x1[2 * k], y[2 * k]);
            s = pk_add(s, z[2 * k]);
            q = pk_fma(z[2 * k], z[2 * k], q);
            z[2 * k + 1] = pk_fma(mB, x1[2 * k + 1], y[2 * k + 1]);
            s = pk_add(s, z[2 * k + 1]);
            q = pk_fma(z[2 * k + 1], z[2 * k + 1], q);
        }
        const float ss = wave_sum64(s.x + s.y);
        const float qq = wave_sum64(q.x + q.y);
        if (lane == 63) red[0][wid] = (v2f){ss, qq};
    }

    v4f   m_cur4 = *(const v4f*)(matrices + 256 + c0);   // m_1 quad
    float dt_cur = delta_t[0];
    float dt_nxt = delta_t[1];
    __syncthreads();

    for (int k = 0; k < NLAYERS - 1; ++k) {
        // Prefetch m_{k+2}/dt_{k+2}; lands under this layer's body.
        const int k2 = (k + 2 < NLAYERS) ? k + 2 : NLAYERS - 1;
        const v4f   m_nxt4 = *(const v4f*)(matrices + k2 * 256 + c0);
        const float dt_nn  = delta_t[k2];

        // Combine 4 wave-partials: 2x ds_read_b128 + 6 adds.
        const int par = k & 1;
        const v4f r0 = *(const v4f*)&red[par][0];   // s0,q0,s1,q1
        const v4f r1 = *(const v4f*)&red[par][2];   // s2,q2,s3,q3
        const float S = (r0.x + r0.z) + (r1.x + r1.z);
        const float Q = (r0.y + r0.w) + (r1.y + r1.w);

        const float dtk  = __builtin_amdgcn_fmed3f(dt_cur, 0.0f, 6.0f);
        const float mean = S * (1.0f / 4096.0f);
        const float var  = fmaf(-mean, mean, Q * (1.0f / 4096.0f));
        const float rstd = rsqrtf(var + 1e-5f);
        const float g    = gp * rstd;            // fold gamma into scale
        const float b    = fmaf(-mean, g, bp);   // fold mean into bias
        const v2f g2 = {g, g}, b2 = {b, b};
        const v2f dt2 = {dtk, dtk};
        const v2f om2 = {1.0f - dtk, 1.0f - dtk};
        const v2f mA = {m_cur4.x, m_cur4.y}, mB = {m_cur4.z, m_cur4.w};

        // Fused pass: apply layer k, build z_{k+1} and its s/q partials.
        v2f s = {0.f, 0.f}, q = {0.f, 0.f};
#pragma unroll
        for (int j = 0; j < 8; ++j) {
            v2f a = pk_fma(z[j], g2, b2);
            a.x = __builtin_amdgcn_fmed3f(a.x, 0.0f, 6.0f);
            a.y = __builtin_amdgcn_fmed3f(a.y, 0.0f, 6.0f);
            y[j] = pk_mul(om2, y[j]);                       // y *= (1-dt)
            y[j] = pk_fma(dt2, a, y[j]);                    // y += dt*a
            z[j] = pk_fma((j & 1) ? mB : mA, x1[j], y[j]);  // next layer z
            s = pk_add(s, z[j]);
            q = pk_fma(z[j], z[j], q);
        }
        const float ss = wave_sum64(s.x + s.y);
        const float qq = wave_sum64(q.x + q.y);
        if (lane == 63) red[par ^ 1][wid] = (v2f){ss, qq};

        m_cur4 = m_nxt4; dt_cur = dt_nxt; dt_nxt = dt_nn;
        __syncthreads();
    }

    // Final layer (k = 29): combine red[1], apply, coalesced scatter y+x1.
    {
        const v4f r0 = *(const v4f*)&red[(NLAYERS - 1) & 1][0];
        const v4f r1 = *(const v4f*)&red[(NLAYERS - 1) & 1][2];
        const float S = (r0.x + r0.z) + (r1.x + r1.z);
        const float Q = (r0.y + r0.w) + (r1.y + r1.w);

        const float dtk  = __builtin_amdgcn_fmed3f(dt_cur, 0.0f, 6.0f);
        const float mean = S * (1.0f / 4096.0f);
        const float var  = fmaf(-mean, mean, Q * (1.0f / 4096.0f));
        const float rstd = rsqrtf(var + 1e-5f);
        const float g    = gp * rstd;
        const float b    = fmaf(-mean, g, bp);
        const v2f g2 = {g, g}, b2 = {b, b};
        const v2f dt2 = {dtk, dtk};
        const v2f om2 = {1.0f - dtk, 1.0f - dtk};

#pragma unroll
        for (int k = 0; k < 4; ++k) {
            v2f o0, o1;
#pragma unroll
            for (int h = 0; h < 2; ++h) {
                const int j = 2 * k + h;
                v2f a = pk_fma(z[j], g2, b2);
                a.x = __builtin_amdgcn_fmed3f(a.x, 0.0f, 6.0f);
                a.y = __builtin_amdgcn_fmed3f(a.y, 0.0f, 6.0f);
                v2f yy = pk_mul(om2, y[j]);
                yy = pk_fma(dt2, a, yy);
                const v2f o = pk_add(yy, x1[j]);
                if (h == 0) o0 = o; else o1 = o;
            }
            v4f o4; o4.x = o0.x; o4.y = o0.y; o4.z = o1.x; o4.w = o1.y;
            *(v4f*)(row + 4 * t + 1024 * k) = o4;   // back into same ws row
        }
    }
}

// ---------------------------------------------------------------------------
// Fallback (proven 55.6 us, round 0): used only if workspace is too small.
// ---------------------------------------------------------------------------
__global__ __launch_bounds__(TPB) void ode_fused(const float* __restrict__ x,
                                                 const float* __restrict__ delta_t,
                                                 const float* __restrict__ matrices,
                                                 const float* __restrict__ gamma,
                                                 const float* __restrict__ beta,
                                                 float* __restrict__ out) {
    const int bid = blockIdx.x;
    const int p   = ((bid & 7) << 7) | (bid >> 3);
    const int t   = threadIdx.x;

    __shared__ float smat[(NLAYERS + 1) * 256];
    __shared__ float sdt[NLAYERS];
    __shared__ __align__(16) v2f red[2][4];

#pragma unroll
    for (int i = 0; i < NLAYERS; ++i)
        smat[i * 256 + t] = matrices[i * 256 + t];
    if (t < NLAYERS)
        sdt[t] = __builtin_amdgcn_fmed3f(delta_t[t], 0.0f, 6.0f);

    v2f x1[8], y[8];
#pragma unroll
    for (int k = 0; k < 8; ++k) {
        x1[k].x = x[(size_t)(t + 512 * k) * HW + p];
        x1[k].y = x[(size_t)(t + 512 * k + 256) * HW + p];
        y[k] = x1[k];
    }

    const float gp   = gamma[p];
    const float bp   = beta[p];
    const int   wid  = t >> 6;
    const int   lane = t & 63;

    __syncthreads();
    float m_cur = smat[t];

    for (int l = 0; l < NLAYERS; ++l) {
        const float dtl = sdt[l];
        const v2f m2    = {m_cur, m_cur};
        const v2f dt2   = {dtl, dtl};
        const v2f om2   = {1.0f - dtl, 1.0f - dtl};

        v2f z[8];
        v2f sA = {0.f, 0.f}, sB = {0.f, 0.f};
        v2f qA = {0.f, 0.f}, qB = {0.f, 0.f};
#pragma unroll
        for (int k = 0; k < 8; k += 2) {
            z[k]     = __builtin_elementwise_fma(m2, x1[k], y[k]);
            z[k + 1] = __builtin_elementwise_fma(m2, x1[k + 1], y[k + 1]);
            sA += z[k];
            sB += z[k + 1];
            qA = __builtin_elementwise_fma(z[k], z[k], qA);
            qB = __builtin_elementwise_fma(z[k + 1], z[k + 1], qB);
        }
#pragma unroll
        for (int k = 0; k < 8; ++k) y[k] *= om2;

        const v2f sv = sA + sB;
        const v2f qv = qA + qB;
        float s = wave_sum64(sv.x + sv.y);
        float q = wave_sum64(qv.x + qv.y);

        const int par = l & 1;
        if (lane == 63) { v2f w; w.x = s; w.y = q; red[par][wid] = w; }
        m_cur = smat[(l + 1) * 256 + t];
        __syncthreads();

        const float4 r0 = *(const float4*)&red[par][0];
        const float4 r1 = *(const float4*)&red[par][2];
        const float S  = (r0.x + r0.z) + (r1.x + r1.z);
        const float S2 = (r0.y + r0.w) + (r1.y + r1.w);

        const float mean = S * (1.0f / 4096.0f);
        const float var  = fmaf(-mean, mean, S2 * (1.0f / 4096.0f));
        const float rstd = rsqrtf(var + 1e-5f);
        const float g    = gp * rstd;
        const float bb   = fmaf(-mean, g, bp);
        const v2f g2 = {g, g}, b2 = {bb, bb};
        const v2f z0 = {0.f, 0.f}, s6 = {6.f, 6.f};
#pragma unroll
        for (int k = 0; k < 8; ++k) {
            v2f a = __builtin_elementwise_fma(z[k], g2, b2);
            a = __builtin_elementwise_max(a, z0);
            a = __builtin_elementwise_min(a, s6);
            y[k] = __builtin_elementwise_fma(dt2, a, y[k]);
        }
    }

#pragma unroll
    for (int k = 0; k < 8; ++k) {
        out[(size_t)(t + 512 * k) * HW + p]       = y[k].x + x1[k].x;
        out[(size_t)(t + 512 * k + 256) * HW + p] = y[k].y + x1[k].y;
    }
}

extern "C" void kernel_launch(void* const* d_in, const int* in_sizes, int n_in,
                              void* d_out, int out_size, void* d_ws, size_t ws_size,
                              hipStream_t stream) {
    const float* x        = (const float*)d_in[0];   // [16,256,32,32]
    const float* delta_t  = (const float*)d_in[1];   // [30,1]
    const float* matrices = (const float*)d_in[2];   // [30,1,1,16,16]
    const float* gamma    = (const float*)d_in[3];   // [1024]
    const float* beta     = (const float*)d_in[4];   // [1024]
    float* out = (float*)d_out;

    const size_t need = (size_t)HW * NROWS * sizeof(float);   // 16 MiB
    if (d_ws != nullptr && ws_size >= need) {
        float* ws = (float*)d_ws;
        // T1: x [4096,1024] -> ws = x^T [1024,4096]
        txp64<<<dim3(HW / 64, NROWS / 64), dim3(TPB), 0, stream>>>(x, ws, NROWS, HW);
        // Main: per-channel rows of ws, in place.
        ode_row<<<dim3(HW), dim3(TPB), 0, stream>>>(ws, delta_t, matrices, gamma, beta);
        // T2: ws [1024,4096] -> out [4096,1024]
        txp64<<<dim3(NROWS / 64, HW / 64), dim3(TPB), 0, stream>>>(ws, out, HW, NROWS);
    } else {
        ode_fused<<<dim3(HW), dim3(TPB), 0, stream>>>(x, delta_t, matrices, gamma, beta, out);
    }
}

// Round 8
// 111.737 us; speedup vs baseline: 1.2244x; 1.0742x over previous
//
#include <hip/hip_runtime.h>

typedef float v2f __attribute__((ext_vector_type(2)));
typedef float v4f __attribute__((ext_vector_type(4)));

#define HW      1024   // H*W = BN channel count (spatial positions)
#define NROWS   4096   // B*C = reduction size per channel
#define NLAYERS 30
#define TPB     256

// ---------------------------------------------------------------------------
// Packed-f32 VOP3P ops.
// ---------------------------------------------------------------------------
static __device__ __forceinline__ v2f pk_fma(v2f a, v2f b, v2f c) {
    v2f d; asm("v_pk_fma_f32 %0, %1, %2, %3" : "=v"(d) : "v"(a), "v"(b), "v"(c));
    return d;
}
static __device__ __forceinline__ v2f pk_add(v2f a, v2f b) {
    v2f d; asm("v_pk_add_f32 %0, %1, %2" : "=v"(d) : "v"(a), "v"(b));
    return d;
}
static __device__ __forceinline__ v2f pk_mul(v2f a, v2f b) {
    v2f d; asm("v_pk_mul_f32 %0, %1, %2" : "=v"(d) : "v"(a), "v"(b));
    return d;
}

// ---------------------------------------------------------------------------
// DPP-based wave64 sum: pure VALU, lane 63 = wave total.
// ---------------------------------------------------------------------------
template <int CTRL, int RMASK>
__device__ __forceinline__ float dpp_add(float x) {
    int t = __builtin_amdgcn_update_dpp(0, __builtin_bit_cast(int, x),
                                        CTRL, RMASK, 0xf, true);
    return x + __builtin_bit_cast(float, t);
}
__device__ __forceinline__ float wave_sum64(float x) {
    x = dpp_add<0x111, 0xf>(x);   // row_shr:1
    x = dpp_add<0x112, 0xf>(x);   // row_shr:2
    x = dpp_add<0x114, 0xf>(x);   // row_shr:4
    x = dpp_add<0x118, 0xf>(x);   // row_shr:8
    x = dpp_add<0x142, 0xa>(x);   // row_bcast15 -> rows 1,3
    x = dpp_add<0x143, 0xc>(x);   // row_bcast31 -> rows 2,3
    return x;                     // lane 63 = wave total
}
__device__ __forceinline__ float bcast63(float x) {
    return __builtin_bit_cast(float,
        __builtin_amdgcn_readlane(__builtin_bit_cast(int, x), 63));
}

// ---------------------------------------------------------------------------
// Generic 64x64-tile transpose (verified R7): dst[n*M+m] = src[m*N+n].
// ---------------------------------------------------------------------------
__global__ __launch_bounds__(TPB) void txp64(const float* __restrict__ src,
                                             float* __restrict__ dst,
                                             int M, int N) {
    __shared__ float tile[64][65];
    const int n0 = blockIdx.x * 64;
    const int m0 = blockIdx.y * 64;
    const int tx = threadIdx.x & 63;
    const int ty = threadIdx.x >> 6;    // 0..3
#pragma unroll
    for (int i = 0; i < 16; ++i) {
        const int r = ty + 4 * i;
        tile[r][tx] = src[(size_t)(m0 + r) * N + n0 + tx];
    }
    __syncthreads();
#pragma unroll
    for (int i = 0; i < 16; ++i) {
        const int r = ty + 4 * i;
        dst[(size_t)(n0 + r) * M + m0 + tx] = tile[tx][r];
    }
}

// ---------------------------------------------------------------------------
// Barrier-free main kernel: ONE wave per channel row of ws (contiguous
// 16 KB). Lane owns e = 4*lane + 256*j + i (j=0..15, i=0..3) -> c = 4*lane+i
// constant in j: one m-quad dwordx4 per layer. All 4096 elems of the BN
// reduction live in THIS wave -> stats = 2 DPP chains + readlane; no LDS,
// no __syncthreads, 30 layers with zero block-wide rendezvous.
// State: x1/y/z = 192 VGPR (+temps); launch_bounds(64,1) -> 512-reg budget.
// Grid 1024 waves = 1 wave/SIMD; per-layer chain hidden by 32-wide ILP.
// ---------------------------------------------------------------------------
__global__ __launch_bounds__(64, 1) void ode_row1w(
    float* ws, const float* __restrict__ delta_t,
    const float* __restrict__ matrices, const float* __restrict__ gamma,
    const float* __restrict__ beta) {

    const int p    = blockIdx.x;
    const int lane = threadIdx.x;            // 0..63
    float* row = ws + (size_t)p * NROWS;

    // Coalesced gather: 16x dwordx4 (1 KB per wave-instruction).
    v2f x1[32], y[32], z[32];
#pragma unroll
    for (int j = 0; j < 16; ++j) {
        const v4f q4 = *(const v4f*)(row + 4 * lane + 256 * j);
        x1[2 * j]     = (v2f){q4.x, q4.y};
        x1[2 * j + 1] = (v2f){q4.z, q4.w};
        y[2 * j]     = x1[2 * j];
        y[2 * j + 1] = x1[2 * j + 1];
    }

    const float gp = gamma[p];
    const float bp = beta[p];

    // s/q accumulators: 4 independent chains each (8-deep FMA chains).
    v2f sa[4], qa[4];

    // Layer 0: z0 = m0*x1 + x1 (y0 = x1).
    {
        const v4f m4 = *(const v4f*)(matrices + 4 * lane);
        const v2f mA = {m4.x, m4.y}, mB = {m4.z, m4.w};
#pragma unroll
        for (int r = 0; r < 4; ++r) { sa[r] = (v2f){0.f, 0.f}; qa[r] = (v2f){0.f, 0.f}; }
#pragma unroll
        for (int j = 0; j < 16; ++j) {
            z[2 * j]     = pk_fma(mA, x1[2 * j], y[2 * j]);
            z[2 * j + 1] = pk_fma(mB, x1[2 * j + 1], y[2 * j + 1]);
            sa[j & 3] = pk_add(sa[j & 3], z[2 * j]);
            qa[j & 3] = pk_fma(z[2 * j], z[2 * j], qa[j & 3]);
            sa[(j + 2) & 3] = pk_add(sa[(j + 2) & 3], z[2 * j + 1]);
            qa[(j + 2) & 3] = pk_fma(z[2 * j + 1], z[2 * j + 1], qa[(j + 2) & 3]);
        }
    }

    v4f   mq  = *(const v4f*)(matrices + 256 + 4 * lane);   // m_1 quad
    float dtc = delta_t[0];
    float dtn = delta_t[1];

    for (int k = 0; k < NLAYERS - 1; ++k) {
        // Prefetch m_{k+2}/dt_{k+2}; lands under stats + pass.
        const int k2 = (k + 2 < NLAYERS) ? k + 2 : NLAYERS - 1;
        const v4f   mq_n  = *(const v4f*)(matrices + k2 * 256 + 4 * lane);
        const float dt_nn = delta_t[k2];

        // In-register stats: combine 4 chains, 2 DPP reductions, readlane.
        const v2f sv = pk_add(pk_add(sa[0], sa[1]), pk_add(sa[2], sa[3]));
        const v2f qv = pk_add(pk_add(qa[0], qa[1]), pk_add(qa[2], qa[3]));
        const float S = bcast63(wave_sum64(sv.x + sv.y));
        const float Q = bcast63(wave_sum64(qv.x + qv.y));

        const float dtk  = __builtin_amdgcn_fmed3f(dtc, 0.0f, 6.0f);
        const float mean = S * (1.0f / 4096.0f);
        const float var  = fmaf(-mean, mean, Q * (1.0f / 4096.0f));
        const float rstd = rsqrtf(var + 1e-5f);
        const float g    = gp * rstd;            // fold gamma into scale
        const float b    = fmaf(-mean, g, bp);   // fold mean into bias
        const v2f g2 = {g, g}, b2 = {b, b};
        const v2f dt2 = {dtk, dtk};
        const v2f om2 = {1.0f - dtk, 1.0f - dtk};
        const v2f mA = {mq.x, mq.y}, mB = {mq.z, mq.w};

#pragma unroll
        for (int r = 0; r < 4; ++r) { sa[r] = (v2f){0.f, 0.f}; qa[r] = (v2f){0.f, 0.f}; }

        // Fused pass: apply layer k, build z_{k+1} and its s/q partials.
#pragma unroll
        for (int j = 0; j < 16; ++j) {
#pragma unroll
            for (int h = 0; h < 2; ++h) {
                const int e = 2 * j + h;
                v2f a = pk_fma(z[e], g2, b2);
                a.x = __builtin_amdgcn_fmed3f(a.x, 0.0f, 6.0f);
                a.y = __builtin_amdgcn_fmed3f(a.y, 0.0f, 6.0f);
                v2f yy = pk_mul(om2, y[e]);          // y *= (1-dt)
                y[e] = pk_fma(dt2, a, yy);           // y += dt*a
                z[e] = pk_fma(h ? mB : mA, x1[e], y[e]);
                sa[(j + 2 * h) & 3] = pk_add(sa[(j + 2 * h) & 3], z[e]);
                qa[(j + 2 * h) & 3] = pk_fma(z[e], z[e], qa[(j + 2 * h) & 3]);
            }
        }

        mq = mq_n; dtc = dtn; dtn = dt_nn;
    }

    // Final layer (k = 29): stats, apply, out = y + x1 back into ws row.
    {
        const v2f sv = pk_add(pk_add(sa[0], sa[1]), pk_add(sa[2], sa[3]));
        const v2f qv = pk_add(pk_add(qa[0], qa[1]), pk_add(qa[2], qa[3]));
        const float S = bcast63(wave_sum64(sv.x + sv.y));
        const float Q = bcast63(wave_sum64(qv.x + qv.y));

        const float dtk  = __builtin_amdgcn_fmed3f(dtc, 0.0f, 6.0f);
        const float mean = S * (1.0f / 4096.0f);
        const float var  = fmaf(-mean, mean, Q * (1.0f / 4096.0f));
        const float rstd = rsqrtf(var + 1e-5f);
        const float g    = gp * rstd;
        const float b    = fmaf(-mean, g, bp);
        const v2f g2 = {g, g}, b2 = {b, b};
        const v2f dt2 = {dtk, dtk};
        const v2f om2 = {1.0f - dtk, 1.0f - dtk};

#pragma unroll
        for (int j = 0; j < 16; ++j) {
            v2f o0, o1;
#pragma unroll
            for (int h = 0; h < 2; ++h) {
                const int e = 2 * j + h;
                v2f a = pk_fma(z[e], g2, b2);
                a.x = __builtin_amdgcn_fmed3f(a.x, 0.0f, 6.0f);
                a.y = __builtin_amdgcn_fmed3f(a.y, 0.0f, 6.0f);
                v2f yy = pk_mul(om2, y[e]);
                yy = pk_fma(dt2, a, yy);
                const v2f o = pk_add(yy, x1[e]);
                if (h == 0) o0 = o; else o1 = o;
            }
            v4f o4; o4.x = o0.x; o4.y = o0.y; o4.z = o1.x; o4.w = o1.y;
            *(v4f*)(row + 4 * lane + 256 * j) = o4;
        }
    }
}

// ---------------------------------------------------------------------------
// Fallback (proven 55.6 us, round 0): used only if workspace is too small.
// ---------------------------------------------------------------------------
__global__ __launch_bounds__(TPB) void ode_fused(const float* __restrict__ x,
                                                 const float* __restrict__ delta_t,
                                                 const float* __restrict__ matrices,
                                                 const float* __restrict__ gamma,
                                                 const float* __restrict__ beta,
                                                 float* __restrict__ out) {
    const int bid = blockIdx.x;
    const int p   = ((bid & 7) << 7) | (bid >> 3);
    const int t   = threadIdx.x;

    __shared__ float smat[(NLAYERS + 1) * 256];
    __shared__ float sdt[NLAYERS];
    __shared__ __align__(16) v2f red[2][4];

#pragma unroll
    for (int i = 0; i < NLAYERS; ++i)
        smat[i * 256 + t] = matrices[i * 256 + t];
    if (t < NLAYERS)
        sdt[t] = __builtin_amdgcn_fmed3f(delta_t[t], 0.0f, 6.0f);

    v2f x1[8], y[8];
#pragma unroll
    for (int k = 0; k < 8; ++k) {
        x1[k].x = x[(size_t)(t + 512 * k) * HW + p];
        x1[k].y = x[(size_t)(t + 512 * k + 256) * HW + p];
        y[k] = x1[k];
    }

    const float gp   = gamma[p];
    const float bp   = beta[p];
    const int   wid  = t >> 6;
    const int   lane = t & 63;

    __syncthreads();
    float m_cur = smat[t];

    for (int l = 0; l < NLAYERS; ++l) {
        const float dtl = sdt[l];
        const v2f m2    = {m_cur, m_cur};
        const v2f dt2   = {dtl, dtl};
        const v2f om2   = {1.0f - dtl, 1.0f - dtl};

        v2f z[8];
        v2f sA = {0.f, 0.f}, sB = {0.f, 0.f};
        v2f qA = {0.f, 0.f}, qB = {0.f, 0.f};
#pragma unroll
        for (int k = 0; k < 8; k += 2) {
            z[k]     = __builtin_elementwise_fma(m2, x1[k], y[k]);
            z[k + 1] = __builtin_elementwise_fma(m2, x1[k + 1], y[k + 1]);
            sA += z[k];
            sB += z[k + 1];
            qA = __builtin_elementwise_fma(z[k], z[k], qA);
            qB = __builtin_elementwise_fma(z[k + 1], z[k + 1], qB);
        }
#pragma unroll
        for (int k = 0; k < 8; ++k) y[k] *= om2;

        const v2f sv = sA + sB;
        const v2f qv = qA + qB;
        float s = wave_sum64(sv.x + sv.y);
        float q = wave_sum64(qv.x + qv.y);

        const int par = l & 1;
        if (lane == 63) { v2f w; w.x = s; w.y = q; red[par][wid] = w; }
        m_cur = smat[(l + 1) * 256 + t];
        __syncthreads();

        const float4 r0 = *(const float4*)&red[par][0];
        const float4 r1 = *(const float4*)&red[par][2];
        const float S  = (r0.x + r0.z) + (r1.x + r1.z);
        const float S2 = (r0.y + r0.w) + (r1.y + r1.w);

        const float mean = S * (1.0f / 4096.0f);
        const float var  = fmaf(-mean, mean, S2 * (1.0f / 4096.0f));
        const float rstd = rsqrtf(var + 1e-5f);
        const float g    = gp * rstd;
        const float bb   = fmaf(-mean, g, bp);
        const v2f g2 = {g, g}, b2 = {bb, bb};
        const v2f z0 = {0.f, 0.f}, s6 = {6.f, 6.f};
#pragma unroll
        for (int k = 0; k < 8; ++k) {
            v2f a = __builtin_elementwise_fma(z[k], g2, b2);
            a = __builtin_elementwise_max(a, z0);
            a = __builtin_elementwise_min(a, s6);
            y[k] = __builtin_elementwise_fma(dt2, a, y[k]);
        }
    }

#pragma unroll
    for (int k = 0; k < 8; ++k) {
        out[(size_t)(t + 512 * k) * HW + p]       = y[k].x + x1[k].x;
        out[(size_t)(t + 512 * k + 256) * HW + p] = y[k].y + x1[k].y;
    }
}

extern "C" void kernel_launch(void* const* d_in, const int* in_sizes, int n_in,
                              void* d_out, int out_size, void* d_ws, size_t ws_size,
                              hipStream_t stream) {
    const float* x        = (const float*)d_in[0];   // [16,256,32,32]
    const float* delta_t  = (const float*)d_in[1];   // [30,1]
    const float* matrices = (const float*)d_in[2];   // [30,1,1,16,16]
    const float* gamma    = (const float*)d_in[3];   // [1024]
    const float* beta     = (const float*)d_in[4];   // [1024]
    float* out = (float*)d_out;

    const size_t need = (size_t)HW * NROWS * sizeof(float);   // 16 MiB
    if (d_ws != nullptr && ws_size >= need) {
        float* ws = (float*)d_ws;
        // T1: x [4096,1024] -> ws = x^T [1024,4096]
        txp64<<<dim3(HW / 64, NROWS / 64), dim3(TPB), 0, stream>>>(x, ws, NROWS, HW);
        // Main: barrier-free, one wave per channel row, in place.
        ode_row1w<<<dim3(HW), dim3(64), 0, stream>>>(ws, delta_t, matrices, gamma, beta);
        // T2: ws [1024,4096] -> out [4096,1024]
        txp64<<<dim3(NROWS / 64, HW / 64), dim3(TPB), 0, stream>>>(ws, out, HW, NROWS);
    } else {
        ode_fused<<<dim3(HW), dim3(TPB), 0, stream>>>(x, delta_t, matrices, gamma, beta, out);
    }
}